// Round 2
// baseline (1281.018 us; speedup 1.0000x reference)
//
#include <hip/hip_runtime.h>

typedef unsigned short ushort_t;
typedef unsigned int uint_t;
typedef __attribute__((ext_vector_type(8))) short s8v;
typedef __attribute__((ext_vector_type(4))) short s4v;
typedef __attribute__((ext_vector_type(4))) float f4v;

#define MFMA(a,b,c) __builtin_amdgcn_mfma_f32_16x16x32_bf16(a,b,c,0,0,0)

__device__ __forceinline__ float bf2f(short s){
  return __uint_as_float(((uint_t)(ushort_t)s) << 16);
}
__device__ __forceinline__ ushort_t f2bf(float f){
  uint_t u = __float_as_uint(f);
  u += 0x7fffu + ((u >> 16) & 1u);
  return (ushort_t)(u >> 16);
}

// ---------------- conversions ----------------
__global__ __launch_bounds__(256) void k_cvt_t(const float* __restrict__ src,
    ushort_t* __restrict__ dst, int R, int C){
  int i = blockIdx.x*256 + threadIdx.x;
  if(i >= R*C) return;
  int r = i / C, c = i - r*C;
  dst[i] = f2bf(src[(size_t)c*R + r]);
}
__global__ __launch_bounds__(256) void k_proj(const float* __restrict__ src,
    ushort_t* __restrict__ dst){
  int i = blockIdx.x*256 + threadIdx.x;
  if(i < 256*64) dst[i] = f2bf(src[i] * 0.3535533905932738f); // * DH^-1/4
}
__global__ __launch_bounds__(256) void k_f2b(const float* __restrict__ s,
    ushort_t* __restrict__ d, int n){
  int i = blockIdx.x*256 + threadIdx.x;
  if(i < n) d[i] = f2bf(s[i]);
}
__global__ __launch_bounds__(256) void k_zero(float* __restrict__ p, int n){
  int i = blockIdx.x*256 + threadIdx.x;
  if(i < n) p[i] = 0.f;
}

// ---------------- generic bf16 GEMM: C[M][N] = A[M][K] * Bt[N][K]^T ----------------
// MODE: 0 plain store, 1 +bias, 2 +bias+ELU.  AF32: A is fp32 (converted during staging)
// lda/ldc: row strides (elements) for A and C.
template<int MODE, int AF32>
__global__ __launch_bounds__(256) void gemm_k(const void* __restrict__ Av, int lda,
    const ushort_t* __restrict__ Bt, ushort_t* __restrict__ Cc, int ldc,
    const float* __restrict__ bias, int M, int N, int K)
{
  __shared__ ushort_t lA[128*32];
  __shared__ ushort_t lB[128*32];
  const int tid = threadIdx.x;
  const int wave = tid>>6, lane = tid&63, quad = lane>>4, lid = lane&15;
  const int row0 = blockIdx.x*128, col0 = blockIdx.y*128;
  const int wr = (wave>>1)*64, wc = (wave&1)*64;
  f4v acc[4][4];
  #pragma unroll
  for(int i=0;i<4;i++)
    #pragma unroll
    for(int j=0;j<4;j++){ f4v z = {0.f,0.f,0.f,0.f}; acc[i][j]=z; }

  const int r0s = tid>>2, c0s = (tid&3)*8;
  const int r1s = r0s + 64;
  const ushort_t* Bb = Bt + (size_t)col0*K;

  for(int k0=0;k0<K;k0+=32){
    s8v a0,a1,b0,b1;
    if(AF32){
      const float* A = (const float*)Av + (size_t)row0*lda;
      f4v u0 = *(const f4v*)(A + (size_t)r0s*lda + k0 + c0s);
      f4v u1 = *(const f4v*)(A + (size_t)r0s*lda + k0 + c0s + 4);
      f4v u2 = *(const f4v*)(A + (size_t)r1s*lda + k0 + c0s);
      f4v u3 = *(const f4v*)(A + (size_t)r1s*lda + k0 + c0s + 4);
      #pragma unroll
      for(int jj=0;jj<4;jj++){
        a0[jj]=(short)f2bf(u0[jj]); a0[4+jj]=(short)f2bf(u1[jj]);
        a1[jj]=(short)f2bf(u2[jj]); a1[4+jj]=(short)f2bf(u3[jj]);
      }
    } else {
      const ushort_t* A = (const ushort_t*)Av + (size_t)row0*lda;
      a0 = *(const s8v*)(A + (size_t)r0s*lda + k0 + c0s);
      a1 = *(const s8v*)(A + (size_t)r1s*lda + k0 + c0s);
    }
    b0 = *(const s8v*)(Bb + (size_t)r0s*K + k0 + c0s);
    b1 = *(const s8v*)(Bb + (size_t)r1s*K + k0 + c0s);
    __syncthreads();               // previous iter's frag reads complete
    *(s8v*)&lA[tid*8]        = a0;
    *(s8v*)&lA[(tid+256)*8]  = a1;
    *(s8v*)&lB[tid*8]        = b0;
    *(s8v*)&lB[(tid+256)*8]  = b1;
    __syncthreads();
    s8v af[4], bfv[4];
    #pragma unroll
    for(int i=0;i<4;i++) af[i]  = *(const s8v*)&lA[(wr+i*16+lid)*32 + quad*8];
    #pragma unroll
    for(int j=0;j<4;j++) bfv[j] = *(const s8v*)&lB[(wc+j*16+lid)*32 + quad*8];
    #pragma unroll
    for(int i=0;i<4;i++)
      #pragma unroll
      for(int j=0;j<4;j++)
        acc[i][j] = MFMA(af[i], bfv[j], acc[i][j]);
  }
  #pragma unroll
  for(int i=0;i<4;i++){
    const int row = row0 + wr + i*16 + quad*4;
    #pragma unroll
    for(int j=0;j<4;j++){
      const int col = col0 + wc + j*16 + lid;
      float bv = 0.f;
      if(MODE>=1) bv = bias[col];
      #pragma unroll
      for(int r=0;r<4;r++){
        float v = acc[i][j][r] + bv;
        if(MODE==2) v = v>0.f ? v : expm1f(v);
        Cc[(size_t)(row+r)*ldc + col] = f2bf(v);
      }
    }
  }
}

// ---------------- global max of dd_k ----------------
__global__ __launch_bounds__(256) void k_ddmax(const ushort_t* __restrict__ qkv,
    const ushort_t* __restrict__ projS, uint_t* __restrict__ maxenc)
{
  const int lt=blockIdx.x, h=blockIdx.y, b=blockIdx.z;
  const int tid=threadIdx.x, wave=tid>>6, lane=tid&63, quad=lane>>4, lid=lane&15;
  const ushort_t* kbase = qkv + (size_t)(b*4096 + lt*64 + wave*16 + lid)*3072 + 1024 + h*64;
  f4v dd[16];
  #pragma unroll
  for(int n=0;n<16;n++){ f4v z={0.f,0.f,0.f,0.f}; dd[n]=z; }
  #pragma unroll
  for(int ks=0;ks<2;ks++){
    s8v af = *(const s8v*)(kbase + ks*32 + quad*8);
    #pragma unroll
    for(int n=0;n<16;n++){
      s8v bfr = *(const s8v*)(projS + (n*16+lid)*64 + ks*32 + quad*8);
      dd[n] = MFMA(af, bfr, dd[n]);
    }
  }
  float m = -1e30f;
  #pragma unroll
  for(int n=0;n<16;n++)
    #pragma unroll
    for(int r=0;r<4;r++) m = fmaxf(m, dd[n][r]);
  for(int o=1;o<64;o<<=1) m = fmaxf(m, __shfl_xor(m, o, 64));
  __shared__ float wmax[4];
  if(lane==0) wmax[wave]=m;
  __syncthreads();
  if(tid==0){
    float mm = fmaxf(fmaxf(wmax[0],wmax[1]), fmaxf(wmax[2],wmax[3]));
    uint_t u = __float_as_uint(mm);
    u = (u & 0x80000000u) ? ~u : (u | 0x80000000u);
    atomicMax(maxenc, u);
  }
}

// ---------------- kv^T and ksum accumulation ----------------
__global__ __launch_bounds__(256) void k_kv(const ushort_t* __restrict__ qkv,
    const ushort_t* __restrict__ projS, const uint_t* __restrict__ maxenc,
    float* __restrict__ kvT, float* __restrict__ ksum)
{
  __shared__ ushort_t lkp[256*72];   // [m][l], stride 72 breaks bank conflicts
  __shared__ ushort_t lvT[64*72];    // [dh][l]
  __shared__ float diag[64];
  const int chunk=blockIdx.x, h=blockIdx.y, b=blockIdx.z;
  const int tid=threadIdx.x, wave=tid>>6, lane=tid&63, quad=lane>>4, lid=lane&15;
  uint_t e = *maxenc;
  float gmax = (e & 0x80000000u) ? __uint_as_float(e & 0x7fffffffu) : __uint_as_float(~e);
  f4v kvacc[4][4];
  #pragma unroll
  for(int mi=0;mi<4;mi++)
    #pragma unroll
    for(int j=0;j<4;j++){ f4v z={0.f,0.f,0.f,0.f}; kvacc[mi][j]=z; }
  float ksacc[16] = {};

  for(int it=0; it<8; it++){
    const int l0 = chunk*512 + it*64;
    __syncthreads();              // previous iter's LDS reads complete
    { // diag partial: thread t -> row t>>2, 16 cols
      const int rr=tid>>2, cc=(tid&3)*16;
      const ushort_t* krow = qkv + (size_t)(b*4096+l0+rr)*3072 + 1024 + h*64 + cc;
      s8v v0=*(const s8v*)krow, v1=*(const s8v*)(krow+8);
      float s=0.f;
      #pragma unroll
      for(int jj=0;jj<8;jj++){ float f0=bf2f(v0[jj]), f1=bf2f(v1[jj]); s+=f0*f0+f1*f1; }
      s += __shfl_xor(s,1,64); s += __shfl_xor(s,2,64);
      if((tid&3)==0) diag[rr] = s*(1.f/16.f);   // 0.5*dn^2 = 1/16
    }
    { // stage v^T
      const int ll=tid&63, dh0=(tid>>6)*16;
      const ushort_t* vrow = qkv + (size_t)(b*4096+l0+ll)*3072 + 2048 + h*64 + dh0;
      s8v v0=*(const s8v*)vrow, v1=*(const s8v*)(vrow+8);
      #pragma unroll
      for(int jj=0;jj<8;jj++){
        lvT[(dh0+jj)*72+ll]   = (ushort_t)v0[jj];
        lvT[(dh0+8+jj)*72+ll] = (ushort_t)v1[jj];
      }
    }
    // dd for this 64-row slab (regs only)
    f4v dd[16];
    #pragma unroll
    for(int n=0;n<16;n++){ f4v z={0.f,0.f,0.f,0.f}; dd[n]=z; }
    const ushort_t* kbase = qkv + (size_t)(b*4096+l0+wave*16+lid)*3072 + 1024 + h*64;
    #pragma unroll
    for(int ks=0;ks<2;ks++){
      s8v af = *(const s8v*)(kbase + ks*32 + quad*8);
      #pragma unroll
      for(int n=0;n<16;n++){
        s8v bfr = *(const s8v*)(projS + (n*16+lid)*64 + ks*32 + quad*8);
        dd[n] = MFMA(af, bfr, dd[n]);
      }
    }
    __syncthreads();              // diag + vT visible
    #pragma unroll
    for(int r=0;r<4;r++){
      const int lrow = wave*16 + quad*4 + r;
      const float dg = diag[lrow];
      #pragma unroll
      for(int n=0;n<16;n++){
        float ekp = __expf(dd[n][r] - dg - gmax) + 1e-6f;
        ksacc[n] += ekp;
        lkp[(n*16+lid)*72 + lrow] = f2bf(ekp);
      }
    }
    __syncthreads();              // lkp ready
    #pragma unroll
    for(int ks=0;ks<2;ks++){
      s8v af[4], bfr[4];
      #pragma unroll
      for(int mi=0;mi<4;mi++) af[mi] = *(const s8v*)&lkp[(wave*64+mi*16+lid)*72 + ks*32+quad*8];
      #pragma unroll
      for(int j=0;j<4;j++)   bfr[j] = *(const s8v*)&lvT[(j*16+lid)*72 + ks*32+quad*8];
      #pragma unroll
      for(int mi=0;mi<4;mi++)
        #pragma unroll
        for(int j=0;j<4;j++) kvacc[mi][j] = MFMA(af[mi], bfr[j], kvacc[mi][j]);
    }
  }
  // ksum: reduce across quads (same lid), add once
  #pragma unroll
  for(int n=0;n<16;n++){
    float s = ksacc[n];
    s += __shfl_xor(s,16,64); s += __shfl_xor(s,32,64);
    if(quad==0) atomicAdd(&ksum[((size_t)b*16+h)*256 + n*16 + lid], s);
  }
  float* kvb = kvT + ((size_t)b*16+h)*(64*256);
  #pragma unroll
  for(int mi=0;mi<4;mi++)
    #pragma unroll
    for(int j=0;j<4;j++)
      #pragma unroll
      for(int r=0;r<4;r++){
        int m  = wave*64 + mi*16 + quad*4 + r;
        int dh = j*16 + lid;
        atomicAdd(&kvb[dh*256 + m], kvacc[mi][j][r]);
      }
}

// ---------------- fused attention (per b,h,64 rows) ----------------
// attnW points at the v-band of qkv (row stride 3072), dead after k_kv.
__global__ __launch_bounds__(256) void k_attn(const ushort_t* __restrict__ qkv,
    const ushort_t* __restrict__ projS, const ushort_t* __restrict__ kvT,
    const float* __restrict__ ksum, ushort_t* __restrict__ attnW)
{
  __shared__ ushort_t lqp[64*264];   // [l][m], stride 264
  __shared__ float diag[64];
  __shared__ float ksl[256];
  const int lt=blockIdx.x, h=blockIdx.y, b=blockIdx.z;
  const int tid=threadIdx.x, wave=tid>>6, lane=tid&63, quad=lane>>4, lid=lane&15;
  const int l0 = lt*64;
  ksl[tid] = ksum[((size_t)b*16+h)*256 + tid];
  {
    const int rr=tid>>2, cc=(tid&3)*16;
    const ushort_t* qrow = qkv + (size_t)(b*4096+l0+rr)*3072 + h*64 + cc;
    s8v v0=*(const s8v*)qrow, v1=*(const s8v*)(qrow+8);
    float s=0.f;
    #pragma unroll
    for(int jj=0;jj<8;jj++){ float f0=bf2f(v0[jj]), f1=bf2f(v1[jj]); s+=f0*f0+f1*f1; }
    s += __shfl_xor(s,1,64); s += __shfl_xor(s,2,64);
    if((tid&3)==0) diag[rr] = s*(1.f/16.f);
  }
  f4v dd[16];
  #pragma unroll
  for(int n=0;n<16;n++){ f4v z={0.f,0.f,0.f,0.f}; dd[n]=z; }
  const ushort_t* qbase = qkv + (size_t)(b*4096+l0+wave*16+lid)*3072 + h*64;
  #pragma unroll
  for(int ks=0;ks<2;ks++){
    s8v af = *(const s8v*)(qbase + ks*32 + quad*8);
    #pragma unroll
    for(int n=0;n<16;n++){
      s8v bfr = *(const s8v*)(projS + (n*16+lid)*64 + ks*32 + quad*8);
      dd[n] = MFMA(af, bfr, dd[n]);
    }
  }
  __syncthreads();                  // diag + ksl ready
  float dnm[4];
  #pragma unroll
  for(int r=0;r<4;r++){
    float m = -1e30f;
    #pragma unroll
    for(int n=0;n<16;n++) m = fmaxf(m, dd[n][r]);
    m = fmaxf(m, __shfl_xor(m,1,64));
    m = fmaxf(m, __shfl_xor(m,2,64));
    m = fmaxf(m, __shfl_xor(m,4,64));
    m = fmaxf(m, __shfl_xor(m,8,64));
    const int lrow = wave*16 + quad*4 + r;
    const float dg = diag[lrow];
    float s = 0.f;
    #pragma unroll
    for(int n=0;n<16;n++){
      float e = __expf(dd[n][r] - dg - m) + 1e-6f;
      s += e * ksl[n*16+lid];
      lqp[lrow*264 + n*16 + lid] = f2bf(e);
    }
    s += __shfl_xor(s,1,64); s += __shfl_xor(s,2,64);
    s += __shfl_xor(s,4,64); s += __shfl_xor(s,8,64);
    dnm[r] = s;
  }
  __syncthreads();                  // lqp ready
  f4v num[4];
  #pragma unroll
  for(int j=0;j<4;j++){ f4v z={0.f,0.f,0.f,0.f}; num[j]=z; }
  const ushort_t* kvb = kvT + ((size_t)b*16+h)*(64*256);
  #pragma unroll
  for(int ks=0;ks<8;ks++){
    s8v af = *(const s8v*)&lqp[(wave*16+lid)*264 + ks*32 + quad*8];
    #pragma unroll
    for(int j=0;j<4;j++){
      s8v bfr = *(const s8v*)(kvb + (size_t)(j*16+lid)*256 + ks*32 + quad*8);
      num[j] = MFMA(af, bfr, num[j]);
    }
  }
  #pragma unroll
  for(int j=0;j<4;j++)
    #pragma unroll
    for(int r=0;r<4;r++){
      const int row = b*4096 + l0 + wave*16 + quad*4 + r;
      attnW[(size_t)row*3072 + h*64 + j*16 + lid] = f2bf(num[j][r] / dnm[r]);
    }
}

// ---------------- LayerNorm ----------------
__device__ __forceinline__ float blockRed(float s, float* buf, int tid){
  #pragma unroll
  for(int o=1;o<64;o<<=1) s += __shfl_xor(s, o, 64);
  __syncthreads();
  if((tid&63)==0) buf[tid>>6] = s;
  __syncthreads();
  return buf[0]+buf[1]+buf[2]+buf[3];
}
template<int FINAL>
__global__ __launch_bounds__(256) void k_ln(const float* __restrict__ xres,
    const ushort_t* __restrict__ aa, int lda_a,
    const ushort_t* __restrict__ bbf, int lda_b,
    const float* __restrict__ g, const float* __restrict__ be,
    ushort_t* __restrict__ obf, int ldo, float* __restrict__ of)
{
  __shared__ float buf[4];
  const int row = blockIdx.x, tid = threadIdx.x;
  float v[4];
  if(FINAL==0){
    f4v xv = *(const f4v*)(xres + (size_t)row*1024 + tid*4);
    s4v av = *(const s4v*)(aa + (size_t)row*lda_a + tid*4);
    #pragma unroll
    for(int i=0;i<4;i++) v[i] = xv[i] + bf2f(av[i]);
  } else {
    s4v av = *(const s4v*)(aa + (size_t)row*lda_a + tid*4);
    s4v bv = *(const s4v*)(bbf + (size_t)row*lda_b + tid*4);
    #pragma unroll
    for(int i=0;i<4;i++) v[i] = bf2f(av[i]) + bf2f(bv[i]);
  }
  float s = v[0]+v[1]+v[2]+v[3];
  s = blockRed(s, buf, tid);
  const float mu = s * (1.f/1024.f);
  float q = 0.f;
  #pragma unroll
  for(int i=0;i<4;i++){ float d=v[i]-mu; q += d*d; }
  q = blockRed(q, buf, tid);
  const float rs = rsqrtf(q*(1.f/1024.f) + 1e-6f);
  const int col = tid*4;
  #pragma unroll
  for(int i=0;i<4;i++){
    float y = (v[i]-mu)*rs*g[col+i] + be[col+i];
    if(FINAL==0) obf[(size_t)row*ldo + col + i] = f2bf(y);
    else         of[(size_t)row*1024 + col + i] = y;
  }
}

// ---------------- launch ----------------
extern "C" void kernel_launch(void* const* d_in, const int* in_sizes, int n_in,
                              void* d_out, int out_size, void* d_ws, size_t ws_size,
                              hipStream_t stream) {
  (void)in_sizes; (void)n_in; (void)out_size; (void)ws_size;
  const float* x    = (const float*)d_in[0];
  const float* wq   = (const float*)d_in[1];
  const float* wk   = (const float*)d_in[2];
  const float* wv   = (const float*)d_in[3];
  const float* wo   = (const float*)d_in[4];
  const float* proj = (const float*)d_in[5];
  const float* ln1g = (const float*)d_in[6];
  const float* ln1b = (const float*)d_in[7];
  const float* ln2g = (const float*)d_in[8];
  const float* ln2b = (const float*)d_in[9];
  const float* w1   = (const float*)d_in[10];
  const float* b1   = (const float*)d_in[11];
  const float* w2   = (const float*)d_in[12];
  const float* b2   = (const float*)d_in[13];

  char* wsb = (char*)d_ws;
  size_t off = 0;
  auto alloc = [&](size_t bytes)->char*{
    char* p = wsb + off; off = (off + bytes + 255) & ~(size_t)255; return p;
  };
  ushort_t* wqkvT = (ushort_t*)alloc(3072ull*1024*2);
  ushort_t* woT   = (ushort_t*)alloc(1024ull*1024*2);
  ushort_t* w1T   = (ushort_t*)alloc(4096ull*1024*2);
  ushort_t* w2T   = (ushort_t*)alloc(1024ull*4096*2);
  ushort_t* projS = (ushort_t*)alloc(256*64*2);
  ushort_t* qkv   = (ushort_t*)alloc(16384ull*3072*2);   // 100.7 MB
  size_t zoff = off;
  float*    kvf   = (float*)alloc(4ull*16*64*256*4);
  float*    ksumb = (float*)alloc(4ull*16*256*4);
  uint_t*   maxenc= (uint_t*)alloc(4);
  size_t zlen = off - zoff;                               // zeroed each call
  ushort_t* kvb   = (ushort_t*)alloc(4ull*16*64*256*2);
  // total ws use: ~132.3 MB

  // overlays on qkv column bands (each band [16384][1024], row stride 3072):
  ushort_t* out1 = qkv;           // q band — dead after k_attn
  ushort_t* ao   = qkv + 1024;    // k band — dead after k_kv
  ushort_t* attn = qkv + 2048;    // v band — dead after k_kv
  ushort_t* ffn  = qkv + 2048;    // v band again — attn dead after wo-GEMM
  // hbuf lives in d_out (dead until final LN), 2 chunks of 8192 rows
  ushort_t* hb   = (ushort_t*)d_out;

  // weight conversions (transposed to [N][K])
  k_cvt_t<<<4096,256,0,stream>>>(wq, wqkvT,                1024, 1024);
  k_cvt_t<<<4096,256,0,stream>>>(wk, wqkvT + 1024ull*1024, 1024, 1024);
  k_cvt_t<<<4096,256,0,stream>>>(wv, wqkvT + 2048ull*1024, 1024, 1024);
  k_cvt_t<<<4096,256,0,stream>>>(wo, woT, 1024, 1024);
  k_cvt_t<<<16384,256,0,stream>>>(w1, w1T, 4096, 1024);
  k_cvt_t<<<16384,256,0,stream>>>(w2, w2T, 1024, 4096);
  k_proj<<<64,256,0,stream>>>(proj, projS);
  {
    int nz = (int)(zlen/4);
    k_zero<<<(nz+255)/256,256,0,stream>>>((float*)(wsb+zoff), nz);
  }

  // QKV projection: [16384,3072] = x[16384,1024] * wqkvT^T
  gemm_k<0,1><<<dim3(128,24),256,0,stream>>>(x, 1024, wqkvT, qkv, 3072, nullptr, 16384, 3072, 1024);
  // global max of dd_k
  k_ddmax<<<dim3(64,16,4),256,0,stream>>>(qkv, projS, maxenc);
  // kv^T + ksum
  k_kv<<<dim3(8,16,4),256,0,stream>>>(qkv, projS, maxenc, kvf, ksumb);
  k_f2b<<<4096,256,0,stream>>>(kvf, kvb, 4*16*64*256);
  // attention numerator/denominator -> v band
  k_attn<<<dim3(64,16,4),256,0,stream>>>(qkv, projS, kvb, ksumb, attn);
  // output projection (v band -> k band) + LN1 (-> q band)
  gemm_k<0,0><<<dim3(128,8),256,0,stream>>>(attn, 3072, woT, ao, 3072, nullptr, 16384, 1024, 1024);
  k_ln<0><<<16384,256,0,stream>>>(x, ao, 3072, nullptr, 0, ln1g, ln1b, out1, 3072, nullptr);
  // FFN in 2 row-chunks of 8192 (hbuf in d_out)
  for(int c=0;c<2;c++){
    const size_t ro = (size_t)c*8192*3072;
    gemm_k<2,0><<<dim3(64,32),256,0,stream>>>(out1 + ro, 3072, w1T, hb, 4096, b1, 8192, 4096, 1024);
    gemm_k<1,0><<<dim3(64,8),256,0,stream>>>(hb, 4096, w2T, ffn + ro, 3072, b2, 8192, 1024, 4096);
  }
  // LN2 -> fp32 out (overwrites all of d_out)
  k_ln<1><<<16384,256,0,stream>>>(nullptr, out1, 3072, ffn, 3072, ln2g, ln2b, nullptr, 0, (float*)d_out);
}

// Round 3
// 1186.539 us; speedup vs baseline: 1.0796x; 1.0796x over previous
//
#include <hip/hip_runtime.h>

typedef unsigned short ushort_t;
typedef unsigned int uint_t;
typedef __attribute__((ext_vector_type(8))) short s8v;
typedef __attribute__((ext_vector_type(4))) short s4v;
typedef __attribute__((ext_vector_type(4))) float f4v;

#define MFMA(a,b,c) __builtin_amdgcn_mfma_f32_16x16x32_bf16(a,b,c,0,0,0)

#define GLDS16(g, l) \
  __builtin_amdgcn_global_load_lds((const __attribute__((address_space(1))) void*)(g), \
                                   (__attribute__((address_space(3))) void*)(l), 16, 0, 0)

__device__ __forceinline__ float bf2f(short s){
  return __uint_as_float(((uint_t)(ushort_t)s) << 16);
}
__device__ __forceinline__ ushort_t f2bf(float f){
  uint_t u = __float_as_uint(f);
  u += 0x7fffu + ((u >> 16) & 1u);
  return (ushort_t)(u >> 16);
}

// ---------------- conversions ----------------
// Transpose-convert: dst[R][C] (bf16) = src[C][R] (fp32). 64x64 tiles via LDS.
__global__ __launch_bounds__(256) void k_cvt_t(const float* __restrict__ src,
    ushort_t* __restrict__ dst, int R, int C){
  __shared__ ushort_t t[64*68];
  const int r0 = blockIdx.x*64, c0 = blockIdx.y*64;
  const int tid = threadIdx.x;
  const int cl = tid>>4, rl4 = (tid&15)*4;   // load: coalesced over r
  #pragma unroll
  for(int cc=0; cc<64; cc+=16){
    f4v v = *(const f4v*)(src + (size_t)(c0+cl+cc)*R + r0 + rl4);
    #pragma unroll
    for(int j=0;j<4;j++) t[(rl4+j)*68 + cl+cc] = f2bf(v[j]);
  }
  __syncthreads();
  const int rw = tid>>4, cw4 = (tid&15)*4;   // store: coalesced over c
  #pragma unroll
  for(int rr=0; rr<64; rr+=16){
    s4v o;
    #pragma unroll
    for(int j=0;j<4;j++) o[j] = (short)t[(rw+rr)*68 + cw4 + j];
    *(s4v*)(dst + (size_t)(r0+rw+rr)*C + c0 + cw4) = o;
  }
}
__global__ __launch_bounds__(256) void k_proj(const float* __restrict__ src,
    ushort_t* __restrict__ dst){
  int i = blockIdx.x*256 + threadIdx.x;
  if(i < 256*64) dst[i] = f2bf(src[i] * 0.3535533905932738f); // * DH^-1/4
}
__global__ __launch_bounds__(256) void k_f2b4(const float* __restrict__ s,
    ushort_t* __restrict__ d, int n4){
  int i = blockIdx.x*256 + threadIdx.x;
  if(i < n4){
    f4v v = ((const f4v*)s)[i];
    s4v o;
    #pragma unroll
    for(int j=0;j<4;j++) o[j] = (short)f2bf(v[j]);
    ((s4v*)d)[i] = o;
  }
}
__global__ __launch_bounds__(256) void k_zero(float* __restrict__ p, int n){
  int i = blockIdx.x*256 + threadIdx.x;
  if(i < n) p[i] = 0.f;
}

// ---------------- bf16 GEMM: C[M][N] = A[M][K] * Bt[N][K]^T ----------------
// MODE: 0 plain store, 1 +bias, 2 +bias+ELU.  lda/ldc: row strides (elements).
// Staging via global_load_lds dwordx4 (m97 structure).
template<int MODE>
__global__ __launch_bounds__(256) void gemm_k(const ushort_t* __restrict__ A, int lda,
    const ushort_t* __restrict__ Bt, ushort_t* __restrict__ Cc, int ldc,
    const float* __restrict__ bias, int M, int N, int K)
{
  __shared__ ushort_t lA[128*32];
  __shared__ ushort_t lB[128*32];
  const int tid = threadIdx.x;
  const int wave = tid>>6, lane = tid&63, quad = lane>>4, lid = lane&15;
  const int row0 = blockIdx.x*128, col0 = blockIdx.y*128;
  const int wr = (wave>>1)*64, wc = (wave&1)*64;
  f4v acc[4][4];
  #pragma unroll
  for(int i=0;i<4;i++)
    #pragma unroll
    for(int j=0;j<4;j++){ f4v z = {0.f,0.f,0.f,0.f}; acc[i][j]=z; }

  // staging: lane l of wave w covers LDS elems [w*512 + l*8 .. +8) (+2048 for 2nd round)
  // -> row = (c? 64:0) + w*16 + (l>>2), col = (l&3)*8
  const int srow = wave*16 + (lane>>2);
  const int scol = (lane&3)*8;
  const ushort_t* Ar0 = A  + (size_t)(row0+srow)*lda + scol;
  const ushort_t* Ar1 = Ar0 + (size_t)64*lda;
  const ushort_t* Br0 = Bt + (size_t)(col0+srow)*K + scol;
  const ushort_t* Br1 = Br0 + (size_t)64*K;
  ushort_t* lA0 = &lA[wave*512];
  ushort_t* lA1 = &lA[2048 + wave*512];
  ushort_t* lB0 = &lB[wave*512];
  ushort_t* lB1 = &lB[2048 + wave*512];

  for(int k0=0;k0<K;k0+=32){
    __syncthreads();               // previous iter's frag reads complete
    GLDS16(Ar0 + k0, lA0);
    GLDS16(Ar1 + k0, lA1);
    GLDS16(Br0 + k0, lB0);
    GLDS16(Br1 + k0, lB1);
    __syncthreads();               // async LDS writes drained (vmcnt before barrier)
    s8v af[4], bfv[4];
    #pragma unroll
    for(int i=0;i<4;i++) af[i]  = *(const s8v*)&lA[(wr+i*16+lid)*32 + quad*8];
    #pragma unroll
    for(int j=0;j<4;j++) bfv[j] = *(const s8v*)&lB[(wc+j*16+lid)*32 + quad*8];
    #pragma unroll
    for(int i=0;i<4;i++)
      #pragma unroll
      for(int j=0;j<4;j++)
        acc[i][j] = MFMA(af[i], bfv[j], acc[i][j]);
  }
  #pragma unroll
  for(int i=0;i<4;i++){
    const int row = row0 + wr + i*16 + quad*4;
    #pragma unroll
    for(int j=0;j<4;j++){
      const int col = col0 + wc + j*16 + lid;
      float bv = 0.f;
      if(MODE>=1) bv = bias[col];
      #pragma unroll
      for(int r=0;r<4;r++){
        float v = acc[i][j][r] + bv;
        if(MODE==2) v = v>0.f ? v : expm1f(v);
        Cc[(size_t)(row+r)*ldc + col] = f2bf(v);
      }
    }
  }
}

// ---------------- global max of dd_k ----------------
__global__ __launch_bounds__(256) void k_ddmax(const ushort_t* __restrict__ qkv,
    const ushort_t* __restrict__ projS, uint_t* __restrict__ maxenc)
{
  const int lt=blockIdx.x, h=blockIdx.y, b=blockIdx.z;
  const int tid=threadIdx.x, wave=tid>>6, lane=tid&63, quad=lane>>4, lid=lane&15;
  const ushort_t* kbase = qkv + (size_t)(b*4096 + lt*64 + wave*16 + lid)*3072 + 1024 + h*64;
  f4v dd[16];
  #pragma unroll
  for(int n=0;n<16;n++){ f4v z={0.f,0.f,0.f,0.f}; dd[n]=z; }
  #pragma unroll
  for(int ks=0;ks<2;ks++){
    s8v af = *(const s8v*)(kbase + ks*32 + quad*8);
    #pragma unroll
    for(int n=0;n<16;n++){
      s8v bfr = *(const s8v*)(projS + (n*16+lid)*64 + ks*32 + quad*8);
      dd[n] = MFMA(af, bfr, dd[n]);
    }
  }
  float m = -1e30f;
  #pragma unroll
  for(int n=0;n<16;n++)
    #pragma unroll
    for(int r=0;r<4;r++) m = fmaxf(m, dd[n][r]);
  for(int o=1;o<64;o<<=1) m = fmaxf(m, __shfl_xor(m, o, 64));
  __shared__ float wmax[4];
  if(lane==0) wmax[wave]=m;
  __syncthreads();
  if(tid==0){
    float mm = fmaxf(fmaxf(wmax[0],wmax[1]), fmaxf(wmax[2],wmax[3]));
    uint_t u = __float_as_uint(mm);
    u = (u & 0x80000000u) ? ~u : (u | 0x80000000u);
    atomicMax(maxenc, u);
  }
}

// ---------------- kv^T and ksum accumulation ----------------
__global__ __launch_bounds__(256) void k_kv(const ushort_t* __restrict__ qkv,
    const ushort_t* __restrict__ projS, const uint_t* __restrict__ maxenc,
    float* __restrict__ kvT, float* __restrict__ ksum)
{
  __shared__ ushort_t lkp[256*72];   // [m][l], stride 72 breaks bank conflicts
  __shared__ ushort_t lvT[64*72];    // [dh][l]
  __shared__ float diag[64];
  const int chunk=blockIdx.x, h=blockIdx.y, b=blockIdx.z;
  const int tid=threadIdx.x, wave=tid>>6, lane=tid&63, quad=lane>>4, lid=lane&15;
  uint_t e = *maxenc;
  float gmax = (e & 0x80000000u) ? __uint_as_float(e & 0x7fffffffu) : __uint_as_float(~e);
  f4v kvacc[4][4];
  #pragma unroll
  for(int mi=0;mi<4;mi++)
    #pragma unroll
    for(int j=0;j<4;j++){ f4v z={0.f,0.f,0.f,0.f}; kvacc[mi][j]=z; }
  float ksacc[16] = {};

  for(int it=0; it<8; it++){
    const int l0 = chunk*512 + it*64;
    __syncthreads();              // previous iter's LDS reads complete
    { // diag partial: thread t -> row t>>2, 16 cols
      const int rr=tid>>2, cc=(tid&3)*16;
      const ushort_t* krow = qkv + (size_t)(b*4096+l0+rr)*3072 + 1024 + h*64 + cc;
      s8v v0=*(const s8v*)krow, v1=*(const s8v*)(krow+8);
      float s=0.f;
      #pragma unroll
      for(int jj=0;jj<8;jj++){ float f0=bf2f(v0[jj]), f1=bf2f(v1[jj]); s+=f0*f0+f1*f1; }
      s += __shfl_xor(s,1,64); s += __shfl_xor(s,2,64);
      if((tid&3)==0) diag[rr] = s*(1.f/16.f);   // 0.5*dn^2 = 1/16
    }
    { // stage v^T
      const int ll=tid&63, dh0=(tid>>6)*16;
      const ushort_t* vrow = qkv + (size_t)(b*4096+l0+ll)*3072 + 2048 + h*64 + dh0;
      s8v v0=*(const s8v*)vrow, v1=*(const s8v*)(vrow+8);
      #pragma unroll
      for(int jj=0;jj<8;jj++){
        lvT[(dh0+jj)*72+ll]   = (ushort_t)v0[jj];
        lvT[(dh0+8+jj)*72+ll] = (ushort_t)v1[jj];
      }
    }
    // dd for this 64-row slab (regs only)
    f4v dd[16];
    #pragma unroll
    for(int n=0;n<16;n++){ f4v z={0.f,0.f,0.f,0.f}; dd[n]=z; }
    const ushort_t* kbase = qkv + (size_t)(b*4096+l0+wave*16+lid)*3072 + 1024 + h*64;
    #pragma unroll
    for(int ks=0;ks<2;ks++){
      s8v af = *(const s8v*)(kbase + ks*32 + quad*8);
      #pragma unroll
      for(int n=0;n<16;n++){
        s8v bfr = *(const s8v*)(projS + (n*16+lid)*64 + ks*32 + quad*8);
        dd[n] = MFMA(af, bfr, dd[n]);
      }
    }
    __syncthreads();              // diag + vT visible
    #pragma unroll
    for(int r=0;r<4;r++){
      const int lrow = wave*16 + quad*4 + r;
      const float dg = diag[lrow];
      #pragma unroll
      for(int n=0;n<16;n++){
        float ekp = __expf(dd[n][r] - dg - gmax) + 1e-6f;
        ksacc[n] += ekp;
        lkp[(n*16+lid)*72 + lrow] = f2bf(ekp);
      }
    }
    __syncthreads();              // lkp ready
    #pragma unroll
    for(int ks=0;ks<2;ks++){
      s8v af[4], bfr[4];
      #pragma unroll
      for(int mi=0;mi<4;mi++) af[mi] = *(const s8v*)&lkp[(wave*64+mi*16+lid)*72 + ks*32+quad*8];
      #pragma unroll
      for(int j=0;j<4;j++)   bfr[j] = *(const s8v*)&lvT[(j*16+lid)*72 + ks*32+quad*8];
      #pragma unroll
      for(int mi=0;mi<4;mi++)
        #pragma unroll
        for(int j=0;j<4;j++) kvacc[mi][j] = MFMA(af[mi], bfr[j], kvacc[mi][j]);
    }
  }
  // ksum: reduce across quads (same lid), add once
  #pragma unroll
  for(int n=0;n<16;n++){
    float s = ksacc[n];
    s += __shfl_xor(s,16,64); s += __shfl_xor(s,32,64);
    if(quad==0) atomicAdd(&ksum[((size_t)b*16+h)*256 + n*16 + lid], s);
  }
  float* kvb = kvT + ((size_t)b*16+h)*(64*256);
  #pragma unroll
  for(int mi=0;mi<4;mi++)
    #pragma unroll
    for(int j=0;j<4;j++)
      #pragma unroll
      for(int r=0;r<4;r++){
        int m  = wave*64 + mi*16 + quad*4 + r;
        int dh = j*16 + lid;
        atomicAdd(&kvb[dh*256 + m], kvacc[mi][j][r]);
      }
}

// ---------------- fused attention (per b,h,64 rows) ----------------
// attnW points at the v-band of qkv (row stride 3072), dead after k_kv.
__global__ __launch_bounds__(256) void k_attn(const ushort_t* __restrict__ qkv,
    const ushort_t* __restrict__ projS, const ushort_t* __restrict__ kvT,
    const float* __restrict__ ksum, ushort_t* __restrict__ attnW)
{
  __shared__ ushort_t lqp[64*264];   // [l][m], stride 264
  __shared__ float diag[64];
  __shared__ float ksl[256];
  const int lt=blockIdx.x, h=blockIdx.y, b=blockIdx.z;
  const int tid=threadIdx.x, wave=tid>>6, lane=tid&63, quad=lane>>4, lid=lane&15;
  const int l0 = lt*64;
  ksl[tid] = ksum[((size_t)b*16+h)*256 + tid];
  {
    const int rr=tid>>2, cc=(tid&3)*16;
    const ushort_t* qrow = qkv + (size_t)(b*4096+l0+rr)*3072 + h*64 + cc;
    s8v v0=*(const s8v*)qrow, v1=*(const s8v*)(qrow+8);
    float s=0.f;
    #pragma unroll
    for(int jj=0;jj<8;jj++){ float f0=bf2f(v0[jj]), f1=bf2f(v1[jj]); s+=f0*f0+f1*f1; }
    s += __shfl_xor(s,1,64); s += __shfl_xor(s,2,64);
    if((tid&3)==0) diag[rr] = s*(1.f/16.f);
  }
  f4v dd[16];
  #pragma unroll
  for(int n=0;n<16;n++){ f4v z={0.f,0.f,0.f,0.f}; dd[n]=z; }
  const ushort_t* qbase = qkv + (size_t)(b*4096+l0+wave*16+lid)*3072 + h*64;
  #pragma unroll
  for(int ks=0;ks<2;ks++){
    s8v af = *(const s8v*)(qbase + ks*32 + quad*8);
    #pragma unroll
    for(int n=0;n<16;n++){
      s8v bfr = *(const s8v*)(projS + (n*16+lid)*64 + ks*32 + quad*8);
      dd[n] = MFMA(af, bfr, dd[n]);
    }
  }
  __syncthreads();                  // diag + ksl ready
  float dnm[4];
  #pragma unroll
  for(int r=0;r<4;r++){
    float m = -1e30f;
    #pragma unroll
    for(int n=0;n<16;n++) m = fmaxf(m, dd[n][r]);
    m = fmaxf(m, __shfl_xor(m,1,64));
    m = fmaxf(m, __shfl_xor(m,2,64));
    m = fmaxf(m, __shfl_xor(m,4,64));
    m = fmaxf(m, __shfl_xor(m,8,64));
    const int lrow = wave*16 + quad*4 + r;
    const float dg = diag[lrow];
    float s = 0.f;
    #pragma unroll
    for(int n=0;n<16;n++){
      float e = __expf(dd[n][r] - dg - m) + 1e-6f;
      s += e * ksl[n*16+lid];
      lqp[lrow*264 + n*16 + lid] = f2bf(e);
    }
    s += __shfl_xor(s,1,64); s += __shfl_xor(s,2,64);
    s += __shfl_xor(s,4,64); s += __shfl_xor(s,8,64);
    dnm[r] = s;
  }
  __syncthreads();                  // lqp ready
  f4v num[4];
  #pragma unroll
  for(int j=0;j<4;j++){ f4v z={0.f,0.f,0.f,0.f}; num[j]=z; }
  const ushort_t* kvb = kvT + ((size_t)b*16+h)*(64*256);
  #pragma unroll
  for(int ks=0;ks<8;ks++){
    s8v af = *(const s8v*)&lqp[(wave*16+lid)*264 + ks*32 + quad*8];
    #pragma unroll
    for(int j=0;j<4;j++){
      s8v bfr = *(const s8v*)(kvb + (size_t)(j*16+lid)*256 + ks*32 + quad*8);
      num[j] = MFMA(af, bfr, num[j]);
    }
  }
  #pragma unroll
  for(int j=0;j<4;j++)
    #pragma unroll
    for(int r=0;r<4;r++){
      const int row = b*4096 + l0 + wave*16 + quad*4 + r;
      attnW[(size_t)row*3072 + h*64 + j*16 + lid] = f2bf(num[j][r] / dnm[r]);
    }
}

// ---------------- LayerNorm ----------------
__device__ __forceinline__ float blockRed(float s, float* buf, int tid){
  #pragma unroll
  for(int o=1;o<64;o<<=1) s += __shfl_xor(s, o, 64);
  __syncthreads();
  if((tid&63)==0) buf[tid>>6] = s;
  __syncthreads();
  return buf[0]+buf[1]+buf[2]+buf[3];
}
template<int FINAL>
__global__ __launch_bounds__(256) void k_ln(const float* __restrict__ xres,
    const ushort_t* __restrict__ aa, int lda_a,
    const ushort_t* __restrict__ bbf, int lda_b,
    const float* __restrict__ g, const float* __restrict__ be,
    ushort_t* __restrict__ obf, int ldo, float* __restrict__ of)
{
  __shared__ float buf[4];
  const int row = blockIdx.x, tid = threadIdx.x;
  float v[4];
  if(FINAL==0){
    f4v xv = *(const f4v*)(xres + (size_t)row*1024 + tid*4);
    s4v av = *(const s4v*)(aa + (size_t)row*lda_a + tid*4);
    #pragma unroll
    for(int i=0;i<4;i++) v[i] = xv[i] + bf2f(av[i]);
  } else {
    s4v av = *(const s4v*)(aa + (size_t)row*lda_a + tid*4);
    s4v bv = *(const s4v*)(bbf + (size_t)row*lda_b + tid*4);
    #pragma unroll
    for(int i=0;i<4;i++) v[i] = bf2f(av[i]) + bf2f(bv[i]);
  }
  float s = v[0]+v[1]+v[2]+v[3];
  s = blockRed(s, buf, tid);
  const float mu = s * (1.f/1024.f);
  float q = 0.f;
  #pragma unroll
  for(int i=0;i<4;i++){ float d=v[i]-mu; q += d*d; }
  q = blockRed(q, buf, tid);
  const float rs = rsqrtf(q*(1.f/1024.f) + 1e-6f);
  const int col = tid*4;
  #pragma unroll
  for(int i=0;i<4;i++){
    float y = (v[i]-mu)*rs*g[col+i] + be[col+i];
    if(FINAL==0) obf[(size_t)row*ldo + col + i] = f2bf(y);
    else         of[(size_t)row*1024 + col + i] = y;
  }
}

// ---------------- launch ----------------
extern "C" void kernel_launch(void* const* d_in, const int* in_sizes, int n_in,
                              void* d_out, int out_size, void* d_ws, size_t ws_size,
                              hipStream_t stream) {
  (void)in_sizes; (void)n_in; (void)out_size; (void)ws_size;
  const float* x    = (const float*)d_in[0];
  const float* wq   = (const float*)d_in[1];
  const float* wk   = (const float*)d_in[2];
  const float* wv   = (const float*)d_in[3];
  const float* wo   = (const float*)d_in[4];
  const float* proj = (const float*)d_in[5];
  const float* ln1g = (const float*)d_in[6];
  const float* ln1b = (const float*)d_in[7];
  const float* ln2g = (const float*)d_in[8];
  const float* ln2b = (const float*)d_in[9];
  const float* w1   = (const float*)d_in[10];
  const float* b1   = (const float*)d_in[11];
  const float* w2   = (const float*)d_in[12];
  const float* b2   = (const float*)d_in[13];

  char* wsb = (char*)d_ws;
  size_t off = 0;
  auto alloc = [&](size_t bytes)->char*{
    char* p = wsb + off; off = (off + bytes + 255) & ~(size_t)255; return p;
  };
  ushort_t* wqkvT = (ushort_t*)alloc(3072ull*1024*2);
  ushort_t* woT   = (ushort_t*)alloc(1024ull*1024*2);
  ushort_t* w1T   = (ushort_t*)alloc(4096ull*1024*2);
  ushort_t* w2T   = (ushort_t*)alloc(1024ull*4096*2);
  ushort_t* projS = (ushort_t*)alloc(256*64*2);
  ushort_t* qkv   = (ushort_t*)alloc(16384ull*3072*2);   // 100.7 MB
  size_t zoff = off;
  float*    kvf   = (float*)alloc(4ull*16*64*256*4);
  float*    ksumb = (float*)alloc(4ull*16*256*4);
  uint_t*   maxenc= (uint_t*)alloc(4);
  size_t zlen = off - zoff;                               // zeroed each call
  ushort_t* kvb   = (ushort_t*)alloc(4ull*16*64*256*2);
  // total ws use: ~132.3 MB

  // overlays on qkv column bands (each band [16384][1024], row stride 3072):
  ushort_t* out1 = qkv;           // q band — dead after k_attn
  ushort_t* ao   = qkv + 1024;    // k band — dead after k_kv
  ushort_t* attn = qkv + 2048;    // v band — dead after k_kv
  ushort_t* ffn  = qkv + 2048;    // v band again — attn dead after wo-GEMM
  // d_out hosts xb (bf16 x) during QKV, then hbuf during FFN, then final fp32 out
  ushort_t* xb   = (ushort_t*)d_out;
  ushort_t* hb   = (ushort_t*)d_out;

  // weight conversions (transposed to [N][K])
  k_cvt_t<<<dim3(16,16),256,0,stream>>>(wq, wqkvT,                1024, 1024);
  k_cvt_t<<<dim3(16,16),256,0,stream>>>(wk, wqkvT + 1024ull*1024, 1024, 1024);
  k_cvt_t<<<dim3(16,16),256,0,stream>>>(wv, wqkvT + 2048ull*1024, 1024, 1024);
  k_cvt_t<<<dim3(16,16),256,0,stream>>>(wo, woT, 1024, 1024);
  k_cvt_t<<<dim3(64,16),256,0,stream>>>(w1, w1T, 4096, 1024);
  k_cvt_t<<<dim3(16,64),256,0,stream>>>(w2, w2T, 1024, 4096);
  k_proj<<<64,256,0,stream>>>(proj, projS);
  k_f2b4<<<16384,256,0,stream>>>(x, xb, 16384*1024/4);
  {
    int nz = (int)(zlen/4);
    k_zero<<<(nz+255)/256,256,0,stream>>>((float*)(wsb+zoff), nz);
  }

  // QKV projection: [16384,3072] = xb[16384,1024] * wqkvT^T
  gemm_k<0><<<dim3(128,24),256,0,stream>>>(xb, 1024, wqkvT, qkv, 3072, nullptr, 16384, 3072, 1024);
  // global max of dd_k
  k_ddmax<<<dim3(64,16,4),256,0,stream>>>(qkv, projS, maxenc);
  // kv^T + ksum
  k_kv<<<dim3(8,16,4),256,0,stream>>>(qkv, projS, maxenc, kvf, ksumb);
  k_f2b4<<<1024,256,0,stream>>>(kvf, kvb, 4*16*64*256/4);
  // attention numerator/denominator -> v band
  k_attn<<<dim3(64,16,4),256,0,stream>>>(qkv, projS, kvb, ksumb, attn);
  // output projection (v band -> k band) + LN1 (-> q band)
  gemm_k<0><<<dim3(128,8),256,0,stream>>>(attn, 3072, woT, ao, 3072, nullptr, 16384, 1024, 1024);
  k_ln<0><<<16384,256,0,stream>>>(x, ao, 3072, nullptr, 0, ln1g, ln1b, out1, 3072, nullptr);
  // FFN in 2 row-chunks of 8192 (hbuf in d_out; xb dead by now)
  for(int c=0;c<2;c++){
    const size_t ro = (size_t)c*8192*3072;
    gemm_k<2><<<dim3(64,32),256,0,stream>>>(out1 + ro, 3072, w1T, hb, 4096, b1, 8192, 4096, 1024);
    gemm_k<1><<<dim3(64,8),256,0,stream>>>(hb, 4096, w2T, ffn + ro, 3072, b2, 8192, 1024, 4096);
  }
  // LN2 -> fp32 out (overwrites all of d_out)
  k_ln<1><<<16384,256,0,stream>>>(nullptr, out1, 3072, ffn, 3072, ln2g, ln2b, nullptr, 0, (float*)d_out);
}

// Round 4
// 1111.341 us; speedup vs baseline: 1.1527x; 1.0677x over previous
//
#include <hip/hip_runtime.h>

typedef unsigned short ushort_t;
typedef unsigned int uint_t;
typedef __attribute__((ext_vector_type(8))) short s8v;
typedef __attribute__((ext_vector_type(4))) short s4v;
typedef __attribute__((ext_vector_type(4))) float f4v;

#define MFMA(a,b,c) __builtin_amdgcn_mfma_f32_16x16x32_bf16(a,b,c,0,0,0)

#define GLDS16(g, l) \
  __builtin_amdgcn_global_load_lds((const __attribute__((address_space(1))) void*)(g), \
                                   (__attribute__((address_space(3))) void*)(l), 16, 0, 0)

__device__ __forceinline__ float bf2f(short s){
  return __uint_as_float(((uint_t)(ushort_t)s) << 16);
}
__device__ __forceinline__ ushort_t f2bf(float f){
  uint_t u = __float_as_uint(f);
  u += 0x7fffu + ((u >> 16) & 1u);
  return (ushort_t)(u >> 16);
}

// ---------------- conversions ----------------
// Transpose-convert: dst[R][C] (bf16) = src[C][R] (fp32). 64x64 tiles via LDS.
__global__ __launch_bounds__(256) void k_cvt_t(const float* __restrict__ src,
    ushort_t* __restrict__ dst, int R, int C){
  __shared__ ushort_t t[64*68];
  const int r0 = blockIdx.x*64, c0 = blockIdx.y*64;
  const int tid = threadIdx.x;
  const int cl = tid>>4, rl4 = (tid&15)*4;   // load: coalesced over r
  #pragma unroll
  for(int cc=0; cc<64; cc+=16){
    f4v v = *(const f4v*)(src + (size_t)(c0+cl+cc)*R + r0 + rl4);
    #pragma unroll
    for(int j=0;j<4;j++) t[(rl4+j)*68 + cl+cc] = f2bf(v[j]);
  }
  __syncthreads();
  const int rw = tid>>4, cw4 = (tid&15)*4;   // store: coalesced over c
  #pragma unroll
  for(int rr=0; rr<64; rr+=16){
    s4v o;
    #pragma unroll
    for(int j=0;j<4;j++) o[j] = (short)t[(rw+rr)*68 + cw4 + j];
    *(s4v*)(dst + (size_t)(r0+rw+rr)*C + c0 + cw4) = o;
  }
}
__global__ __launch_bounds__(256) void k_proj(const float* __restrict__ src,
    ushort_t* __restrict__ dst){
  int i = blockIdx.x*256 + threadIdx.x;
  if(i < 256*64) dst[i] = f2bf(src[i] * 0.3535533905932738f); // * DH^-1/4
}
__global__ __launch_bounds__(256) void k_f2b4(const float* __restrict__ s,
    ushort_t* __restrict__ d, int n4){
  int i = blockIdx.x*256 + threadIdx.x;
  if(i < n4){
    f4v v = ((const f4v*)s)[i];
    s4v o;
    #pragma unroll
    for(int j=0;j<4;j++) o[j] = (short)f2bf(v[j]);
    ((s4v*)d)[i] = o;
  }
}
__global__ __launch_bounds__(256) void k_zero(float* __restrict__ p, int n){
  int i = blockIdx.x*256 + threadIdx.x;
  if(i < n) p[i] = 0.f;
}

// ---------------- bf16 GEMM: C[M][N] = A[M][K] * Bt[N][K]^T ----------------
// MODE: 0 plain store, 1 +bias, 2 +bias+ELU.  lda/ldc: row strides (elements).
// Staging via global_load_lds dwordx4 (m97 structure).
template<int MODE>
__global__ __launch_bounds__(256) void gemm_k(const ushort_t* __restrict__ A, int lda,
    const ushort_t* __restrict__ Bt, ushort_t* __restrict__ Cc, int ldc,
    const float* __restrict__ bias, int M, int N, int K)
{
  __shared__ ushort_t lA[128*32];
  __shared__ ushort_t lB[128*32];
  const int tid = threadIdx.x;
  const int wave = tid>>6, lane = tid&63, quad = lane>>4, lid = lane&15;
  const int row0 = blockIdx.x*128, col0 = blockIdx.y*128;
  const int wr = (wave>>1)*64, wc = (wave&1)*64;
  f4v acc[4][4];
  #pragma unroll
  for(int i=0;i<4;i++)
    #pragma unroll
    for(int j=0;j<4;j++){ f4v z = {0.f,0.f,0.f,0.f}; acc[i][j]=z; }

  const int srow = wave*16 + (lane>>2);
  const int scol = (lane&3)*8;
  const ushort_t* Ar0 = A  + (size_t)(row0+srow)*lda + scol;
  const ushort_t* Ar1 = Ar0 + (size_t)64*lda;
  const ushort_t* Br0 = Bt + (size_t)(col0+srow)*K + scol;
  const ushort_t* Br1 = Br0 + (size_t)64*K;
  ushort_t* lA0 = &lA[wave*512];
  ushort_t* lA1 = &lA[2048 + wave*512];
  ushort_t* lB0 = &lB[wave*512];
  ushort_t* lB1 = &lB[2048 + wave*512];

  for(int k0=0;k0<K;k0+=32){
    __syncthreads();               // previous iter's frag reads complete
    GLDS16(Ar0 + k0, lA0);
    GLDS16(Ar1 + k0, lA1);
    GLDS16(Br0 + k0, lB0);
    GLDS16(Br1 + k0, lB1);
    __syncthreads();               // async LDS writes drained
    s8v af[4], bfv[4];
    #pragma unroll
    for(int i=0;i<4;i++) af[i]  = *(const s8v*)&lA[(wr+i*16+lid)*32 + quad*8];
    #pragma unroll
    for(int j=0;j<4;j++) bfv[j] = *(const s8v*)&lB[(wc+j*16+lid)*32 + quad*8];
    #pragma unroll
    for(int i=0;i<4;i++)
      #pragma unroll
      for(int j=0;j<4;j++)
        acc[i][j] = MFMA(af[i], bfv[j], acc[i][j]);
  }
  #pragma unroll
  for(int i=0;i<4;i++){
    const int row = row0 + wr + i*16 + quad*4;
    #pragma unroll
    for(int j=0;j<4;j++){
      const int col = col0 + wc + j*16 + lid;
      float bv = 0.f;
      if(MODE>=1) bv = bias[col];
      #pragma unroll
      for(int r=0;r<4;r++){
        float v = acc[i][j][r] + bv;
        if(MODE==2) v = v>0.f ? v : expm1f(v);
        Cc[(size_t)(row+r)*ldc + col] = f2bf(v);
      }
    }
  }
}

// ---------------- kv^T and ksum accumulation ----------------
// Grid: (chunk=8 [512 l-rows], mt=4 [64 m-feats], h+16*b). No global max needed:
// the softmax-kernel scale factor cancels exactly in num/denom (eps asym ~1e-6).
__global__ __launch_bounds__(256) void k_kv(const ushort_t* __restrict__ qkv,
    const ushort_t* __restrict__ projS,
    float* __restrict__ kvT, float* __restrict__ ksum)
{
  __shared__ ushort_t lkp[64*72];    // [m-within-mt][l], stride 72
  __shared__ ushort_t lvT[64*72];    // [dh][l]
  __shared__ float diag[64];
  const int chunk=blockIdx.x, mt=blockIdx.y;
  const int h=blockIdx.z&15, b=blockIdx.z>>4;
  const int tid=threadIdx.x, wave=tid>>6, lane=tid&63, quad=lane>>4, lid=lane&15;
  f4v kvacc[4];
  #pragma unroll
  for(int j=0;j<4;j++){ f4v z={0.f,0.f,0.f,0.f}; kvacc[j]=z; }
  float ksacc[4] = {};
  const ushort_t* projM = projS + mt*64*64;

  for(int it=0; it<8; it++){
    const int l0 = chunk*512 + it*64;
    __syncthreads();              // previous iter's LDS reads complete
    { // diag partial: thread t -> row t>>2, 16 cols
      const int rr=tid>>2, cc=(tid&3)*16;
      const ushort_t* krow = qkv + (size_t)(b*4096+l0+rr)*3072 + 1024 + h*64 + cc;
      s8v v0=*(const s8v*)krow, v1=*(const s8v*)(krow+8);
      float s=0.f;
      #pragma unroll
      for(int jj=0;jj<8;jj++){ float f0=bf2f(v0[jj]), f1=bf2f(v1[jj]); s+=f0*f0+f1*f1; }
      s += __shfl_xor(s,1,64); s += __shfl_xor(s,2,64);
      if((tid&3)==0) diag[rr] = s*(1.f/16.f);   // 0.5*dn^2 = 1/16
    }
    { // stage v^T
      const int ll=tid&63, dh0=(tid>>6)*16;
      const ushort_t* vrow = qkv + (size_t)(b*4096+l0+ll)*3072 + 2048 + h*64 + dh0;
      s8v v0=*(const s8v*)vrow, v1=*(const s8v*)(vrow+8);
      #pragma unroll
      for(int jj=0;jj<8;jj++){
        lvT[(dh0+jj)*72+ll]   = (ushort_t)v0[jj];
        lvT[(dh0+8+jj)*72+ll] = (ushort_t)v1[jj];
      }
    }
    // dd for this 64-row slab, 64 m-features (regs only)
    f4v dd[4];
    #pragma unroll
    for(int n=0;n<4;n++){ f4v z={0.f,0.f,0.f,0.f}; dd[n]=z; }
    const ushort_t* kbase = qkv + (size_t)(b*4096+l0+wave*16+lid)*3072 + 1024 + h*64;
    #pragma unroll
    for(int ks=0;ks<2;ks++){
      s8v af = *(const s8v*)(kbase + ks*32 + quad*8);
      #pragma unroll
      for(int n=0;n<4;n++){
        s8v bfr = *(const s8v*)(projM + (n*16+lid)*64 + ks*32 + quad*8);
        dd[n] = MFMA(af, bfr, dd[n]);
      }
    }
    __syncthreads();              // diag + vT visible
    const int lrb = wave*16 + quad*4;
    float dgs[4];
    #pragma unroll
    for(int r=0;r<4;r++) dgs[r] = diag[lrb+r];
    #pragma unroll
    for(int n=0;n<4;n++){
      s4v pk;
      #pragma unroll
      for(int r=0;r<4;r++){
        float ekp = __expf(dd[n][r] - dgs[r]) + 1e-6f;
        ksacc[n] += ekp;
        pk[r] = (short)f2bf(ekp);
      }
      *(s4v*)&lkp[(n*16+lid)*72 + lrb] = pk;   // b64 write, l-contiguous
    }
    __syncthreads();              // lkp ready
    #pragma unroll
    for(int ks=0;ks<2;ks++){
      s8v af = *(const s8v*)&lkp[(wave*16+lid)*72 + ks*32+quad*8];
      #pragma unroll
      for(int j=0;j<4;j++){
        s8v bfr = *(const s8v*)&lvT[(j*16+lid)*72 + ks*32+quad*8];
        kvacc[j] = MFMA(af, bfr, kvacc[j]);
      }
    }
  }
  // ksum: reduce across quads (same lid), add once per wave
  #pragma unroll
  for(int n=0;n<4;n++){
    float s = ksacc[n];
    s += __shfl_xor(s,16,64); s += __shfl_xor(s,32,64);
    if(quad==0) atomicAdd(&ksum[((size_t)b*16+h)*256 + mt*64 + n*16 + lid], s);
  }
  float* kvb = kvT + ((size_t)b*16+h)*(64*256);
  #pragma unroll
  for(int j=0;j<4;j++)
    #pragma unroll
    for(int r=0;r<4;r++){
      int m  = mt*64 + wave*16 + quad*4 + r;
      int dh = j*16 + lid;
      atomicAdd(&kvb[dh*256 + m], kvacc[j][r]);
    }
}

// ---------------- fused attention (per b,h,64 rows) ----------------
// Per-row max and q-side diag dropped: per-row scale factors cancel in num/denom.
// attnW points at the v-band of qkv (row stride 3072), dead after k_kv.
__global__ __launch_bounds__(256) void k_attn(const ushort_t* __restrict__ qkv,
    const ushort_t* __restrict__ projS, const ushort_t* __restrict__ kvT,
    const float* __restrict__ ksum, ushort_t* __restrict__ attnW)
{
  __shared__ ushort_t lqp[64*264];   // [l][m], stride 264
  __shared__ float ksl[256];
  const int lt=blockIdx.x, h=blockIdx.y, b=blockIdx.z;
  const int tid=threadIdx.x, wave=tid>>6, lane=tid&63, quad=lane>>4, lid=lane&15;
  const int l0 = lt*64;
  ksl[tid] = ksum[((size_t)b*16+h)*256 + tid];
  f4v dd[16];
  #pragma unroll
  for(int n=0;n<16;n++){ f4v z={0.f,0.f,0.f,0.f}; dd[n]=z; }
  const ushort_t* qbase = qkv + (size_t)(b*4096+l0+wave*16+lid)*3072 + h*64;
  #pragma unroll
  for(int ks=0;ks<2;ks++){
    s8v af = *(const s8v*)(qbase + ks*32 + quad*8);
    #pragma unroll
    for(int n=0;n<16;n++){
      s8v bfr = *(const s8v*)(projS + (n*16+lid)*64 + ks*32 + quad*8);
      dd[n] = MFMA(af, bfr, dd[n]);
    }
  }
  __syncthreads();                  // ksl ready
  float dnm[4];
  #pragma unroll
  for(int r=0;r<4;r++){
    const int lrow = wave*16 + quad*4 + r;
    float s = 0.f;
    #pragma unroll
    for(int n=0;n<16;n++){
      float e = __expf(dd[n][r]) + 1e-6f;
      s += e * ksl[n*16+lid];
      lqp[lrow*264 + n*16 + lid] = f2bf(e);
    }
    s += __shfl_xor(s,1,64); s += __shfl_xor(s,2,64);
    s += __shfl_xor(s,4,64); s += __shfl_xor(s,8,64);
    dnm[r] = s;
  }
  __syncthreads();                  // lqp ready
  f4v num[4];
  #pragma unroll
  for(int j=0;j<4;j++){ f4v z={0.f,0.f,0.f,0.f}; num[j]=z; }
  const ushort_t* kvb = kvT + ((size_t)b*16+h)*(64*256);
  #pragma unroll
  for(int ks=0;ks<8;ks++){
    s8v af = *(const s8v*)&lqp[(wave*16+lid)*264 + ks*32 + quad*8];
    #pragma unroll
    for(int j=0;j<4;j++){
      s8v bfr = *(const s8v*)(kvb + (size_t)(j*16+lid)*256 + ks*32 + quad*8);
      num[j] = MFMA(af, bfr, num[j]);
    }
  }
  #pragma unroll
  for(int j=0;j<4;j++)
    #pragma unroll
    for(int r=0;r<4;r++){
      const int row = b*4096 + l0 + wave*16 + quad*4 + r;
      attnW[(size_t)row*3072 + h*64 + j*16 + lid] = f2bf(num[j][r] / dnm[r]);
    }
}

// ---------------- LayerNorm ----------------
__device__ __forceinline__ float blockRed(float s, float* buf, int tid){
  #pragma unroll
  for(int o=1;o<64;o<<=1) s += __shfl_xor(s, o, 64);
  __syncthreads();
  if((tid&63)==0) buf[tid>>6] = s;
  __syncthreads();
  return buf[0]+buf[1]+buf[2]+buf[3];
}
template<int FINAL>
__global__ __launch_bounds__(256) void k_ln(const float* __restrict__ xres,
    const ushort_t* __restrict__ aa, int lda_a,
    const ushort_t* __restrict__ bbf, int lda_b,
    const float* __restrict__ g, const float* __restrict__ be,
    ushort_t* __restrict__ obf, int ldo, float* __restrict__ of)
{
  __shared__ float buf[4];
  const int row = blockIdx.x, tid = threadIdx.x;
  float v[4];
  if(FINAL==0){
    f4v xv = *(const f4v*)(xres + (size_t)row*1024 + tid*4);
    s4v av = *(const s4v*)(aa + (size_t)row*lda_a + tid*4);
    #pragma unroll
    for(int i=0;i<4;i++) v[i] = xv[i] + bf2f(av[i]);
  } else {
    s4v av = *(const s4v*)(aa + (size_t)row*lda_a + tid*4);
    s4v bv = *(const s4v*)(bbf + (size_t)row*lda_b + tid*4);
    #pragma unroll
    for(int i=0;i<4;i++) v[i] = bf2f(av[i]) + bf2f(bv[i]);
  }
  float s = v[0]+v[1]+v[2]+v[3];
  s = blockRed(s, buf, tid);
  const float mu = s * (1.f/1024.f);
  float q = 0.f;
  #pragma unroll
  for(int i=0;i<4;i++){ float d=v[i]-mu; q += d*d; }
  q = blockRed(q, buf, tid);
  const float rs = rsqrtf(q*(1.f/1024.f) + 1e-6f);
  const int col = tid*4;
  #pragma unroll
  for(int i=0;i<4;i++){
    float y = (v[i]-mu)*rs*g[col+i] + be[col+i];
    if(FINAL==0) obf[(size_t)row*ldo + col + i] = f2bf(y);
    else         of[(size_t)row*1024 + col + i] = y;
  }
}

// ---------------- launch ----------------
extern "C" void kernel_launch(void* const* d_in, const int* in_sizes, int n_in,
                              void* d_out, int out_size, void* d_ws, size_t ws_size,
                              hipStream_t stream) {
  (void)in_sizes; (void)n_in; (void)out_size; (void)ws_size;
  const float* x    = (const float*)d_in[0];
  const float* wq   = (const float*)d_in[1];
  const float* wk   = (const float*)d_in[2];
  const float* wv   = (const float*)d_in[3];
  const float* wo   = (const float*)d_in[4];
  const float* proj = (const float*)d_in[5];
  const float* ln1g = (const float*)d_in[6];
  const float* ln1b = (const float*)d_in[7];
  const float* ln2g = (const float*)d_in[8];
  const float* ln2b = (const float*)d_in[9];
  const float* w1   = (const float*)d_in[10];
  const float* b1   = (const float*)d_in[11];
  const float* w2   = (const float*)d_in[12];
  const float* b2   = (const float*)d_in[13];

  char* wsb = (char*)d_ws;
  size_t off = 0;
  auto alloc = [&](size_t bytes)->char*{
    char* p = wsb + off; off = (off + bytes + 255) & ~(size_t)255; return p;
  };
  ushort_t* wqkvT = (ushort_t*)alloc(3072ull*1024*2);
  ushort_t* woT   = (ushort_t*)alloc(1024ull*1024*2);
  ushort_t* w1T   = (ushort_t*)alloc(4096ull*1024*2);
  ushort_t* w2T   = (ushort_t*)alloc(1024ull*4096*2);
  ushort_t* projS = (ushort_t*)alloc(256*64*2);
  ushort_t* qkv   = (ushort_t*)alloc(16384ull*3072*2);   // 100.7 MB
  size_t zoff = off;
  float*    kvf   = (float*)alloc(4ull*16*64*256*4);
  float*    ksumb = (float*)alloc(4ull*16*256*4);
  size_t zlen = off - zoff;                               // zeroed each call
  ushort_t* kvb   = (ushort_t*)alloc(4ull*16*64*256*2);
  // total ws use: ~132.3 MB

  // overlays on qkv column bands (each band [16384][1024], row stride 3072):
  ushort_t* out1 = qkv;           // q band — dead after k_attn
  ushort_t* ao   = qkv + 1024;    // k band — dead after k_kv
  ushort_t* attn = qkv + 2048;    // v band — dead after k_kv
  ushort_t* ffn  = qkv + 2048;    // v band again — attn dead after wo-GEMM
  // d_out hosts xb (bf16 x) during QKV, then hbuf during FFN, then final fp32 out
  ushort_t* xb   = (ushort_t*)d_out;
  ushort_t* hb   = (ushort_t*)d_out;

  // weight conversions (transposed to [N][K])
  k_cvt_t<<<dim3(16,16),256,0,stream>>>(wq, wqkvT,                1024, 1024);
  k_cvt_t<<<dim3(16,16),256,0,stream>>>(wk, wqkvT + 1024ull*1024, 1024, 1024);
  k_cvt_t<<<dim3(16,16),256,0,stream>>>(wv, wqkvT + 2048ull*1024, 1024, 1024);
  k_cvt_t<<<dim3(16,16),256,0,stream>>>(wo, woT, 1024, 1024);
  k_cvt_t<<<dim3(64,16),256,0,stream>>>(w1, w1T, 4096, 1024);
  k_cvt_t<<<dim3(16,64),256,0,stream>>>(w2, w2T, 1024, 4096);
  k_proj<<<64,256,0,stream>>>(proj, projS);
  k_f2b4<<<16384,256,0,stream>>>(x, xb, 16384*1024/4);
  {
    int nz = (int)(zlen/4);
    k_zero<<<(nz+255)/256,256,0,stream>>>((float*)(wsb+zoff), nz);
  }

  // QKV projection: [16384,3072] = xb[16384,1024] * wqkvT^T
  gemm_k<0><<<dim3(128,24),256,0,stream>>>(xb, 1024, wqkvT, qkv, 3072, nullptr, 16384, 3072, 1024);
  // kv^T + ksum (no global-max pass needed)
  k_kv<<<dim3(8,4,64),256,0,stream>>>(qkv, projS, kvf, ksumb);
  k_f2b4<<<1024,256,0,stream>>>(kvf, kvb, 4*16*64*256/4);
  // attention numerator/denominator -> v band
  k_attn<<<dim3(64,16,4),256,0,stream>>>(qkv, projS, kvb, ksumb, attn);
  // output projection (v band -> k band) + LN1 (-> q band)
  gemm_k<0><<<dim3(128,8),256,0,stream>>>(attn, 3072, woT, ao, 3072, nullptr, 16384, 1024, 1024);
  k_ln<0><<<16384,256,0,stream>>>(x, ao, 3072, nullptr, 0, ln1g, ln1b, out1, 3072, nullptr);
  // FFN in 2 row-chunks of 8192 (hbuf in d_out; xb dead by now)
  for(int c=0;c<2;c++){
    const size_t ro = (size_t)c*8192*3072;
    gemm_k<2><<<dim3(64,32),256,0,stream>>>(out1 + ro, 3072, w1T, hb, 4096, b1, 8192, 4096, 1024);
    gemm_k<1><<<dim3(64,8),256,0,stream>>>(hb, 4096, w2T, ffn + ro, 3072, b2, 8192, 1024, 4096);
  }
  // LN2 -> fp32 out (overwrites all of d_out)
  k_ln<1><<<16384,256,0,stream>>>(nullptr, out1, 3072, ffn, 3072, ln2g, ln2b, nullptr, 0, (float*)d_out);
}

// Round 5
// 1027.432 us; speedup vs baseline: 1.2468x; 1.0817x over previous
//
#include <hip/hip_runtime.h>

typedef unsigned short ushort_t;
typedef unsigned int uint_t;
typedef __attribute__((ext_vector_type(8))) short s8v;
typedef __attribute__((ext_vector_type(4))) short s4v;
typedef __attribute__((ext_vector_type(4))) float f4v;

#define MFMA(a,b,c) __builtin_amdgcn_mfma_f32_16x16x32_bf16(a,b,c,0,0,0)

#define GLDS16(g, l) \
  __builtin_amdgcn_global_load_lds((const __attribute__((address_space(1))) void*)(g), \
                                   (__attribute__((address_space(3))) void*)(l), 16, 0, 0)

__device__ __forceinline__ float bf2f(short s){
  return __uint_as_float(((uint_t)(ushort_t)s) << 16);
}
__device__ __forceinline__ ushort_t f2bf(float f){
  uint_t u = __float_as_uint(f);
  u += 0x7fffu + ((u >> 16) & 1u);
  return (ushort_t)(u >> 16);
}

// ---------------- conversions ----------------
// Transpose-convert: dst[R][C] (bf16) = src[C][R] (fp32). 64x64 tiles via LDS.
__global__ __launch_bounds__(256) void k_cvt_t(const float* __restrict__ src,
    ushort_t* __restrict__ dst, int R, int C){
  __shared__ ushort_t t[64*68];
  const int r0 = blockIdx.x*64, c0 = blockIdx.y*64;
  const int tid = threadIdx.x;
  const int cl = tid>>4, rl4 = (tid&15)*4;   // load: coalesced over r
  #pragma unroll
  for(int cc=0; cc<64; cc+=16){
    f4v v = *(const f4v*)(src + (size_t)(c0+cl+cc)*R + r0 + rl4);
    #pragma unroll
    for(int j=0;j<4;j++) t[(rl4+j)*68 + cl+cc] = f2bf(v[j]);
  }
  __syncthreads();
  const int rw = tid>>4, cw4 = (tid&15)*4;   // store: coalesced over c
  #pragma unroll
  for(int rr=0; rr<64; rr+=16){
    s4v o;
    #pragma unroll
    for(int j=0;j<4;j++) o[j] = (short)t[(rw+rr)*68 + cw4 + j];
    *(s4v*)(dst + (size_t)(r0+rw+rr)*C + c0 + cw4) = o;
  }
}
__global__ __launch_bounds__(256) void k_proj(const float* __restrict__ src,
    ushort_t* __restrict__ dst){
  int i = blockIdx.x*256 + threadIdx.x;
  if(i < 256*64) dst[i] = f2bf(src[i] * 0.3535533905932738f); // * DH^-1/4
}
__global__ __launch_bounds__(256) void k_f2b4(const float* __restrict__ s,
    ushort_t* __restrict__ d, int n4){
  int i = blockIdx.x*256 + threadIdx.x;
  if(i < n4){
    f4v v = ((const f4v*)s)[i];
    s4v o;
    #pragma unroll
    for(int j=0;j<4;j++) o[j] = (short)f2bf(v[j]);
    ((s4v*)d)[i] = o;
  }
}
__global__ __launch_bounds__(256) void k_zero(float* __restrict__ p, int n){
  int i = blockIdx.x*256 + threadIdx.x;
  if(i < n) p[i] = 0.f;
}

// ---------------- bf16 GEMM: C[M][N] = A[M][K] * Bt[N][K]^T ----------------
template<int MODE>
__global__ __launch_bounds__(256) void gemm_k(const ushort_t* __restrict__ A, int lda,
    const ushort_t* __restrict__ Bt, ushort_t* __restrict__ Cc, int ldc,
    const float* __restrict__ bias, int M, int N, int K)
{
  __shared__ ushort_t lA[128*32];
  __shared__ ushort_t lB[128*32];
  const int tid = threadIdx.x;
  const int wave = tid>>6, lane = tid&63, quad = lane>>4, lid = lane&15;
  const int row0 = blockIdx.x*128, col0 = blockIdx.y*128;
  const int wr = (wave>>1)*64, wc = (wave&1)*64;
  f4v acc[4][4];
  #pragma unroll
  for(int i=0;i<4;i++)
    #pragma unroll
    for(int j=0;j<4;j++){ f4v z = {0.f,0.f,0.f,0.f}; acc[i][j]=z; }

  const int srow = wave*16 + (lane>>2);
  const int scol = (lane&3)*8;
  const ushort_t* Ar0 = A  + (size_t)(row0+srow)*lda + scol;
  const ushort_t* Ar1 = Ar0 + (size_t)64*lda;
  const ushort_t* Br0 = Bt + (size_t)(col0+srow)*K + scol;
  const ushort_t* Br1 = Br0 + (size_t)64*K;
  ushort_t* lA0 = &lA[wave*512];
  ushort_t* lA1 = &lA[2048 + wave*512];
  ushort_t* lB0 = &lB[wave*512];
  ushort_t* lB1 = &lB[2048 + wave*512];

  for(int k0=0;k0<K;k0+=32){
    __syncthreads();
    GLDS16(Ar0 + k0, lA0);
    GLDS16(Ar1 + k0, lA1);
    GLDS16(Br0 + k0, lB0);
    GLDS16(Br1 + k0, lB1);
    __syncthreads();
    s8v af[4], bfv[4];
    #pragma unroll
    for(int i=0;i<4;i++) af[i]  = *(const s8v*)&lA[(wr+i*16+lid)*32 + quad*8];
    #pragma unroll
    for(int j=0;j<4;j++) bfv[j] = *(const s8v*)&lB[(wc+j*16+lid)*32 + quad*8];
    #pragma unroll
    for(int i=0;i<4;i++)
      #pragma unroll
      for(int j=0;j<4;j++)
        acc[i][j] = MFMA(af[i], bfv[j], acc[i][j]);
  }
  #pragma unroll
  for(int i=0;i<4;i++){
    const int row = row0 + wr + i*16 + quad*4;
    #pragma unroll
    for(int j=0;j<4;j++){
      const int col = col0 + wc + j*16 + lid;
      float bv = 0.f;
      if(MODE>=1) bv = bias[col];
      #pragma unroll
      for(int r=0;r<4;r++){
        float v = acc[i][j][r] + bv;
        if(MODE==2) v = v>0.f ? v : expm1f(v);
        Cc[(size_t)(row+r)*ldc + col] = f2bf(v);
      }
    }
  }
}

// ---------------- kv^T partials + ksum ----------------
// Grid (chunk=4, mt=4, bh=64). Each block: 16 slabs of 64 l-rows, 64 m-feats.
// K staged via global_load_lds with XOR col-block swizzle; V transposed via LDS;
// kp round-trips LDS (C-layout -> A-layout). Writes fp32 partial kv[m][dh]
// (no atomics); k_f2bt reduces 4 partials and transposes to bf16 [dh][m].
__global__ __launch_bounds__(256) void k_kv(const ushort_t* __restrict__ qkv,
    const ushort_t* __restrict__ projS,
    float* __restrict__ kvp, float* __restrict__ ksum)
{
  __shared__ ushort_t lK[64*64];       // [l][cb^(l&7) swizzled], no pad (glds)
  __shared__ ushort_t lvT[2][64*72];   // [dh][l], stride 72
  __shared__ ushort_t lkp[64*72];      // [m][l], stride 72
  const int chunk=blockIdx.x, mt=blockIdx.y, bh=blockIdx.z;
  const int h=bh&15, b=bh>>4;
  const int tid=threadIdx.x, wave=tid>>6, lane=tid&63, quad=lane>>4, lid=lane&15;

  // proj fragments held in registers for all iterations
  s8v pf[4][2];
  {
    const ushort_t* projM = projS + mt*64*64;
    #pragma unroll
    for(int n=0;n<4;n++)
      #pragma unroll
      for(int ks=0;ks<2;ks++)
        pf[n][ks] = *(const s8v*)(projM + (n*16+lid)*64 + ks*32 + quad*8);
  }
  f4v kvacc[4];
  #pragma unroll
  for(int j=0;j<4;j++){ f4v z={0.f,0.f,0.f,0.f}; kvacc[j]=z; }
  float ksacc[4] = {};

  // K staging pointers (swizzled source, lane-linear LDS dest)
  const int sl = tid>>3;               // slab row 0..31 (per round)
  const int gcb = (tid&7) ^ (sl&7);    // swizzled global col-block
  const size_t lbase = (size_t)(b*4096 + chunk*1024);
  const ushort_t* gK0 = qkv + (lbase + sl     )*3072 + 1024 + h*64 + gcb*8;
  const ushort_t* gK1 = qkv + (lbase + sl + 32)*3072 + 1024 + h*64 + gcb*8;
  ushort_t* lK0 = &lK[(wave*8     )*64];
  ushort_t* lK1 = &lK[(wave*8 + 32)*64];
  // V staging pointer: thread covers l=lane, dh wave*16..+16
  const ushort_t* gV = qkv + (lbase + lane)*3072 + 2048 + h*64 + wave*16;

  for(int it=0; it<16; it++){
    const int p = it&1;
    GLDS16(gK0, lK0);
    GLDS16(gK1, lK1);
    {
      s8v v0 = *(const s8v*)gV;
      s8v v1 = *(const s8v*)(gV + 8);
      #pragma unroll
      for(int jj=0;jj<8;jj++){
        lvT[p][(wave*16+jj  )*72 + lane] = (ushort_t)v0[jj];
        lvT[p][(wave*16+8+jj)*72 + lane] = (ushort_t)v1[jj];
      }
    }
    gK0 += 64*3072; gK1 += 64*3072; gV += 64*3072;
    __syncthreads();                 // B1: glds drained + vT visible
    // diag for this wave's 16 rows (4 lanes per row)
    float dv;
    {
      const int rl = wave*16 + (lane>>2);
      const int cb0 = 2*(lane&3);
      s8v u0 = *(const s8v*)&lK[rl*64 + ((cb0  )^(rl&7))*8];
      s8v u1 = *(const s8v*)&lK[rl*64 + ((cb0+1)^(rl&7))*8];
      float s = 0.f;
      #pragma unroll
      for(int jj=0;jj<8;jj++){
        float f0=bf2f(u0[jj]), f1=bf2f(u1[jj]);
        s += f0*f0 + f1*f1;
      }
      s += __shfl_xor(s,1,64); s += __shfl_xor(s,2,64);
      dv = s*(1.f/16.f);             // 0.5*dn^2 = 1/16
    }
    // dd MFMA from swizzled lK
    f4v dd[4];
    #pragma unroll
    for(int n=0;n<4;n++){ f4v z={0.f,0.f,0.f,0.f}; dd[n]=z; }
    {
      const int ra = wave*16 + lid;
      #pragma unroll
      for(int ks=0;ks<2;ks++){
        s8v af = *(const s8v*)&lK[ra*64 + ((ks*4+quad)^(ra&7))*8];
        #pragma unroll
        for(int n=0;n<4;n++) dd[n] = MFMA(af, pf[n][ks], dd[n]);
      }
    }
    // kp = exp(dd - diag) + eps -> lkp (A-layout)
    const int lrb = wave*16 + quad*4;
    #pragma unroll
    for(int n=0;n<4;n++){
      s4v pk;
      #pragma unroll
      for(int r=0;r<4;r++){
        float dg = __shfl(dv, (quad*4+r)*4, 64);
        float ekp = __expf(dd[n][r] - dg) + 1e-6f;
        ksacc[n] += ekp;
        pk[r] = (short)f2bf(ekp);
      }
      *(s4v*)&lkp[(n*16+lid)*72 + lrb] = pk;
    }
    __syncthreads();                 // B2: lkp ready
    #pragma unroll
    for(int ks=0;ks<2;ks++){
      s8v af = *(const s8v*)&lkp[(wave*16+lid)*72 + ks*32 + quad*8];
      #pragma unroll
      for(int j=0;j<4;j++){
        s8v bfr = *(const s8v*)&lvT[p][(j*16+lid)*72 + ks*32 + quad*8];
        kvacc[j] = MFMA(af, bfr, kvacc[j]);
      }
    }
  }
  // ksum: reduce across quads, one atomic per (n,lid) per wave
  #pragma unroll
  for(int n=0;n<4;n++){
    float s = ksacc[n];
    s += __shfl_xor(s,16,64); s += __shfl_xor(s,32,64);
    if(quad==0) atomicAdd(&ksum[((size_t)b*16+h)*256 + mt*64 + n*16 + lid], s);
  }
  // partial kv store: [m][dh], coalesced 64B per quad-group
  float* kvo = kvp + ((size_t)chunk*64 + bh)*16384;
  #pragma unroll
  for(int j=0;j<4;j++)
    #pragma unroll
    for(int r=0;r<4;r++)
      kvo[(mt*64 + wave*16 + quad*4 + r)*64 + j*16 + lid] = kvacc[j][r];
}

// ---------------- reduce 4 kv partials + transpose to bf16 [dh][m] ----------------
__global__ __launch_bounds__(256) void k_f2bt(const float* __restrict__ kvp,
    ushort_t* __restrict__ kvb)
{
  __shared__ ushort_t tb[64*68];   // [m-local][dh]
  const int mt=blockIdx.x, bh=blockIdx.y;
  const int tid=threadIdx.x;
  {
    const int ml=tid>>2, dg=(tid&3)*16;
    float s[16];
    #pragma unroll
    for(int e=0;e<16;e++) s[e]=0.f;
    #pragma unroll
    for(int c=0;c<4;c++){
      const float* pb = kvp + ((size_t)(c*64+bh)*256 + mt*64+ml)*64 + dg;
      #pragma unroll
      for(int e4=0;e4<4;e4++){
        f4v v = *(const f4v*)(pb + e4*4);
        #pragma unroll
        for(int j=0;j<4;j++) s[e4*4+j] += v[j];
      }
    }
    #pragma unroll
    for(int e=0;e<16;e++) tb[ml*68 + dg + e] = f2bf(s[e]);
  }
  __syncthreads();
  {
    const int dh=tid>>2, mg=(tid&3)*16;
    ushort_t* ob = kvb + (size_t)bh*16384 + (size_t)dh*256 + mt*64 + mg;
    #pragma unroll
    for(int e4=0;e4<4;e4++){
      s4v o;
      #pragma unroll
      for(int j=0;j<4;j++) o[j] = (short)tb[(mg+e4*4+j)*68 + dh];
      *(s4v*)(ob + e4*4) = o;
    }
  }
}

// ---------------- fused attention (per b,h,64 rows) ----------------
__global__ __launch_bounds__(256) void k_attn(const ushort_t* __restrict__ qkv,
    const ushort_t* __restrict__ projS, const ushort_t* __restrict__ kvT,
    const float* __restrict__ ksum, ushort_t* __restrict__ attnW)
{
  __shared__ ushort_t lqp[64*264];   // [l][m], stride 264
  __shared__ float ksl[256];
  const int lt=blockIdx.x, h=blockIdx.y, b=blockIdx.z;
  const int tid=threadIdx.x, wave=tid>>6, lane=tid&63, quad=lane>>4, lid=lane&15;
  const int l0 = lt*64;
  ksl[tid] = ksum[((size_t)b*16+h)*256 + tid];
  f4v dd[16];
  #pragma unroll
  for(int n=0;n<16;n++){ f4v z={0.f,0.f,0.f,0.f}; dd[n]=z; }
  const ushort_t* qbase = qkv + (size_t)(b*4096+l0+wave*16+lid)*3072 + h*64;
  #pragma unroll
  for(int ks=0;ks<2;ks++){
    s8v af = *(const s8v*)(qbase + ks*32 + quad*8);
    #pragma unroll
    for(int n=0;n<16;n++){
      s8v bfr = *(const s8v*)(projS + (n*16+lid)*64 + ks*32 + quad*8);
      dd[n] = MFMA(af, bfr, dd[n]);
    }
  }
  __syncthreads();                  // ksl ready
  float dnm[4];
  #pragma unroll
  for(int r=0;r<4;r++){
    const int lrow = wave*16 + quad*4 + r;
    float s = 0.f;
    #pragma unroll
    for(int n=0;n<16;n++){
      float e = __expf(dd[n][r]) + 1e-6f;
      s += e * ksl[n*16+lid];
      lqp[lrow*264 + n*16 + lid] = f2bf(e);
    }
    s += __shfl_xor(s,1,64); s += __shfl_xor(s,2,64);
    s += __shfl_xor(s,4,64); s += __shfl_xor(s,8,64);
    dnm[r] = s;
  }
  __syncthreads();                  // lqp ready
  f4v num[4];
  #pragma unroll
  for(int j=0;j<4;j++){ f4v z={0.f,0.f,0.f,0.f}; num[j]=z; }
  const ushort_t* kvb = kvT + ((size_t)b*16+h)*(64*256);
  #pragma unroll
  for(int ks=0;ks<8;ks++){
    s8v af = *(const s8v*)&lqp[(wave*16+lid)*264 + ks*32 + quad*8];
    #pragma unroll
    for(int j=0;j<4;j++){
      s8v bfr = *(const s8v*)(kvb + (size_t)(j*16+lid)*256 + ks*32 + quad*8);
      num[j] = MFMA(af, bfr, num[j]);
    }
  }
  #pragma unroll
  for(int j=0;j<4;j++)
    #pragma unroll
    for(int r=0;r<4;r++){
      const int row = b*4096 + l0 + wave*16 + quad*4 + r;
      attnW[(size_t)row*3072 + h*64 + j*16 + lid] = f2bf(num[j][r] / dnm[r]);
    }
}

// ---------------- LayerNorm ----------------
__device__ __forceinline__ float blockRed(float s, float* buf, int tid){
  #pragma unroll
  for(int o=1;o<64;o<<=1) s += __shfl_xor(s, o, 64);
  __syncthreads();
  if((tid&63)==0) buf[tid>>6] = s;
  __syncthreads();
  return buf[0]+buf[1]+buf[2]+buf[3];
}
template<int FINAL>
__global__ __launch_bounds__(256) void k_ln(const float* __restrict__ xres,
    const ushort_t* __restrict__ aa, int lda_a,
    const ushort_t* __restrict__ bbf, int lda_b,
    const float* __restrict__ g, const float* __restrict__ be,
    ushort_t* __restrict__ obf, int ldo, float* __restrict__ of)
{
  __shared__ float buf[4];
  const int row = blockIdx.x, tid = threadIdx.x;
  float v[4];
  if(FINAL==0){
    f4v xv = *(const f4v*)(xres + (size_t)row*1024 + tid*4);
    s4v av = *(const s4v*)(aa + (size_t)row*lda_a + tid*4);
    #pragma unroll
    for(int i=0;i<4;i++) v[i] = xv[i] + bf2f(av[i]);
  } else {
    s4v av = *(const s4v*)(aa + (size_t)row*lda_a + tid*4);
    s4v bv = *(const s4v*)(bbf + (size_t)row*lda_b + tid*4);
    #pragma unroll
    for(int i=0;i<4;i++) v[i] = bf2f(av[i]) + bf2f(bv[i]);
  }
  float s = v[0]+v[1]+v[2]+v[3];
  s = blockRed(s, buf, tid);
  const float mu = s * (1.f/1024.f);
  float q = 0.f;
  #pragma unroll
  for(int i=0;i<4;i++){ float d=v[i]-mu; q += d*d; }
  q = blockRed(q, buf, tid);
  const float rs = rsqrtf(q*(1.f/1024.f) + 1e-6f);
  const int col = tid*4;
  #pragma unroll
  for(int i=0;i<4;i++){
    float y = (v[i]-mu)*rs*g[col+i] + be[col+i];
    if(FINAL==0) obf[(size_t)row*ldo + col + i] = f2bf(y);
    else         of[(size_t)row*1024 + col + i] = y;
  }
}

// ---------------- launch ----------------
extern "C" void kernel_launch(void* const* d_in, const int* in_sizes, int n_in,
                              void* d_out, int out_size, void* d_ws, size_t ws_size,
                              hipStream_t stream) {
  (void)in_sizes; (void)n_in; (void)out_size; (void)ws_size;
  const float* x    = (const float*)d_in[0];
  const float* wq   = (const float*)d_in[1];
  const float* wk   = (const float*)d_in[2];
  const float* wv   = (const float*)d_in[3];
  const float* wo   = (const float*)d_in[4];
  const float* proj = (const float*)d_in[5];
  const float* ln1g = (const float*)d_in[6];
  const float* ln1b = (const float*)d_in[7];
  const float* ln2g = (const float*)d_in[8];
  const float* ln2b = (const float*)d_in[9];
  const float* w1   = (const float*)d_in[10];
  const float* b1   = (const float*)d_in[11];
  const float* w2   = (const float*)d_in[12];
  const float* b2   = (const float*)d_in[13];

  char* wsb = (char*)d_ws;
  size_t off = 0;
  auto alloc = [&](size_t bytes)->char*{
    char* p = wsb + off; off = (off + bytes + 255) & ~(size_t)255; return p;
  };
  ushort_t* wqkvT = (ushort_t*)alloc(3072ull*1024*2);
  ushort_t* woT   = (ushort_t*)alloc(1024ull*1024*2);
  ushort_t* w1T   = (ushort_t*)alloc(4096ull*1024*2);
  ushort_t* w2T   = (ushort_t*)alloc(1024ull*4096*2);
  ushort_t* projS = (ushort_t*)alloc(256*64*2);
  ushort_t* qkv   = (ushort_t*)alloc(16384ull*3072*2);   // 100.7 MB
  size_t zoff = off;
  float*    ksumb = (float*)alloc(4ull*16*256*4);
  size_t zlen = off - zoff;                               // zeroed each call
  ushort_t* kvb   = (ushort_t*)alloc(4ull*16*64*256*2);
  // total ws use: ~134 MB

  // overlays on qkv column bands (each band [16384][1024], row stride 3072):
  ushort_t* out1 = qkv;           // q band — dead after k_attn
  ushort_t* ao   = qkv + 1024;    // k band — dead after k_kv
  ushort_t* attn = qkv + 2048;    // v band — dead after k_kv
  ushort_t* ffn  = qkv + 2048;    // v band again — attn dead after wo-GEMM
  // d_out timeline: xb (bf16 x, QKV phase) -> kvp (fp32 kv partials, 64 MB)
  //                 -> hbuf (FFN phase) -> final fp32 out
  ushort_t* xb   = (ushort_t*)d_out;
  float*    kvp  = (float*)d_out;
  ushort_t* hb   = (ushort_t*)d_out;

  // weight conversions (transposed to [N][K])
  k_cvt_t<<<dim3(16,16),256,0,stream>>>(wq, wqkvT,                1024, 1024);
  k_cvt_t<<<dim3(16,16),256,0,stream>>>(wk, wqkvT + 1024ull*1024, 1024, 1024);
  k_cvt_t<<<dim3(16,16),256,0,stream>>>(wv, wqkvT + 2048ull*1024, 1024, 1024);
  k_cvt_t<<<dim3(16,16),256,0,stream>>>(wo, woT, 1024, 1024);
  k_cvt_t<<<dim3(64,16),256,0,stream>>>(w1, w1T, 4096, 1024);
  k_cvt_t<<<dim3(16,64),256,0,stream>>>(w2, w2T, 1024, 4096);
  k_proj<<<64,256,0,stream>>>(proj, projS);
  k_f2b4<<<16384,256,0,stream>>>(x, xb, 16384*1024/4);
  {
    int nz = (int)(zlen/4);
    k_zero<<<(nz+255)/256,256,0,stream>>>((float*)(wsb+zoff), nz);
  }

  // QKV projection: [16384,3072] = xb[16384,1024] * wqkvT^T
  gemm_k<0><<<dim3(128,24),256,0,stream>>>(xb, 1024, wqkvT, qkv, 3072, nullptr, 16384, 3072, 1024);
  // kv partials + ksum (xb dead; kvp overlays d_out)
  k_kv<<<dim3(4,4,64),256,0,stream>>>(qkv, projS, kvp, ksumb);
  // reduce partials + transpose -> bf16 kvb [dh][m]
  k_f2bt<<<dim3(4,64),256,0,stream>>>(kvp, kvb);
  // attention numerator/denominator -> v band
  k_attn<<<dim3(64,16,4),256,0,stream>>>(qkv, projS, kvb, ksumb, attn);
  // output projection (v band -> k band) + LN1 (-> q band)
  gemm_k<0><<<dim3(128,8),256,0,stream>>>(attn, 3072, woT, ao, 3072, nullptr, 16384, 1024, 1024);
  k_ln<0><<<16384,256,0,stream>>>(x, ao, 3072, nullptr, 0, ln1g, ln1b, out1, 3072, nullptr);
  // FFN in 2 row-chunks of 8192 (hbuf in d_out; kvp dead by now)
  for(int c=0;c<2;c++){
    const size_t ro = (size_t)c*8192*3072;
    gemm_k<2><<<dim3(64,32),256,0,stream>>>(out1 + ro, 3072, w1T, hb, 4096, b1, 8192, 4096, 1024);
    gemm_k<1><<<dim3(64,8),256,0,stream>>>(hb, 4096, w2T, ffn + ro, 3072, b2, 8192, 1024, 4096);
  }
  // LN2 -> fp32 out (overwrites all of d_out)
  k_ln<1><<<16384,256,0,stream>>>(nullptr, out1, 3072, ffn, 3072, ln2g, ln2b, nullptr, 0, (float*)d_out);
}